// Round 3
// baseline (367.600 us; speedup 1.0000x reference)
//
#include <hip/hip_runtime.h>
#include <math.h>

namespace {
constexpr int kB = 8, kC = 64, kD = 32, kH = 64, kW = 64;
constexpr int kHW      = kH * kW;        // 4096
constexpr int kDHW     = kD * kHW;       // 131072
constexpr int kSpatial = kB * kDHW;      // 1048576
constexpr int kCs4     = kDHW / 4;       // channel stride in float4 units
}

// Kernel 1: per-spatial-position mean and max over the 64 channels.
// One thread = 4 consecutive w positions (float4). Fully coalesced:
// a wave reads 1 KiB contiguous per channel step.
__global__ __launch_bounds__(256) void reduce_mean_max(
        const float* __restrict__ x,
        float* __restrict__ avg,
        float* __restrict__ mx) {
    int tid = blockIdx.x * blockDim.x + threadIdx.x;   // [0, kSpatial/4)
    int s   = tid * 4;                                  // flat spatial index
    int b   = s / kDHW;
    int rem = s - b * kDHW;
    const float4* xp = (const float4*)(x + (size_t)b * (size_t)kC * kDHW + rem);

    float4 sum = make_float4(0.f, 0.f, 0.f, 0.f);
    float4 m   = make_float4(-INFINITY, -INFINITY, -INFINITY, -INFINITY);
    #pragma unroll 8
    for (int c = 0; c < kC; ++c) {
        float4 t = xp[(size_t)c * kCs4];
        sum.x += t.x; sum.y += t.y; sum.z += t.z; sum.w += t.w;
        m.x = fmaxf(m.x, t.x); m.y = fmaxf(m.y, t.y);
        m.z = fmaxf(m.z, t.z); m.w = fmaxf(m.w, t.w);
    }
    const float inv = 1.0f / (float)kC;
    float4 a = make_float4(sum.x * inv, sum.y * inv, sum.z * inv, sum.w * inv);
    ((float4*)avg)[tid] = a;
    ((float4*)mx)[tid]  = m;
}

// Kernel 2: 3x3x3 cross-correlation over [avg, max], SAME zero pad, fused
// sigmoid. Each thread computes 4 consecutive w outputs: per contributing
// (dd,hh) row it loads one aligned float4 + 2 edge scalars per input array
// (27 loads/output vs 54 scalar before), writes a float4.
__global__ __launch_bounds__(256) void conv_sigmoid(
        const float* __restrict__ avg,
        const float* __restrict__ mx,
        const float* __restrict__ wts,
        float* __restrict__ out) {
    __shared__ float w[54];
    if (threadIdx.x < 54) w[threadIdx.x] = wts[threadIdx.x];
    __syncthreads();

    int tid = blockIdx.x * blockDim.x + threadIdx.x;   // [0, kSpatial/4)
    int w0 = (tid & 15) * 4;          // 0..60
    int h  = (tid >> 4) & (kH - 1);
    int bd = tid >> 10;               // b*kD + d
    int d  = bd & (kD - 1);
    int b  = bd >> 5;

    float acc[4] = {0.f, 0.f, 0.f, 0.f};

    #pragma unroll
    for (int kd = 0; kd < 3; ++kd) {
        int dd = d + kd - 1;
        if (dd < 0 || dd >= kD) continue;
        #pragma unroll
        for (int kh = 0; kh < 3; ++kh) {
            int hh = h + kh - 1;
            if (hh < 0 || hh >= kH) continue;
            size_t rowbase = (size_t)b * kDHW + (size_t)dd * kHW + (size_t)hh * kW + w0;
            const int wbase = (kd * 3 + kh) * 3;

            // positions w0-1 .. w0+4 for both arrays
            float4 va = *(const float4*)(avg + rowbase);
            float4 vm = *(const float4*)(mx + rowbase);
            float la = (w0 > 0)        ? avg[rowbase - 1] : 0.f;
            float lm = (w0 > 0)        ? mx[rowbase - 1]  : 0.f;
            float ra = (w0 + 4 < kW)   ? avg[rowbase + 4] : 0.f;
            float rm = (w0 + 4 < kW)   ? mx[rowbase + 4]  : 0.f;

            float lva[6] = {la, va.x, va.y, va.z, va.w, ra};
            float lvm[6] = {lm, vm.x, vm.y, vm.z, vm.w, rm};

            #pragma unroll
            for (int kw = 0; kw < 3; ++kw) {
                float wa = w[wbase + kw];
                float wb = w[27 + wbase + kw];
                #pragma unroll
                for (int j = 0; j < 4; ++j) {
                    acc[j] = fmaf(lva[j + kw], wa, acc[j]);
                    acc[j] = fmaf(lvm[j + kw], wb, acc[j]);
                }
            }
        }
    }

    float4 o;
    o.x = 1.0f / (1.0f + expf(-acc[0]));
    o.y = 1.0f / (1.0f + expf(-acc[1]));
    o.z = 1.0f / (1.0f + expf(-acc[2]));
    o.w = 1.0f / (1.0f + expf(-acc[3]));
    ((float4*)out)[tid] = o;
}

extern "C" void kernel_launch(void* const* d_in, const int* in_sizes, int n_in,
                              void* d_out, int out_size, void* d_ws, size_t ws_size,
                              hipStream_t stream) {
    const float* x   = (const float*)d_in[0];
    const float* wts = (const float*)d_in[1];
    float* out = (float*)d_out;

    float* avg = (float*)d_ws;            // kSpatial floats (4 MiB)
    float* mx  = avg + kSpatial;          // kSpatial floats (4 MiB)

    {
        int threads = 256;
        int blocks  = (kSpatial / 4) / threads;   // 1024
        reduce_mean_max<<<blocks, threads, 0, stream>>>(x, avg, mx);
    }
    {
        int threads = 256;
        int blocks  = (kSpatial / 4) / threads;   // 1024
        conv_sigmoid<<<blocks, threads, 0, stream>>>(avg, mx, wts, out);
    }
}